// Round 11
// baseline (355.116 us; speedup 1.0000x reference)
//
#include <hip/hip_runtime.h>
#include <cstdint>
#include <cstddef>

#define DEV __device__ __forceinline__

typedef _Float16 v4h __attribute__((ext_vector_type(4)));
typedef float    v4f __attribute__((ext_vector_type(4)));

DEV float fsig(float x)  { return __builtin_amdgcn_rcpf(1.0f + __expf(-x)); }
DEV float ftanh_(float x){ return 1.0f - 2.0f * __builtin_amdgcn_rcpf(1.0f + __expf(2.0f * x)); }
DEV float swz16f(float v) {   // lane ^ 16 within each 32-lane half
    return __uint_as_float(__builtin_amdgcn_ds_swizzle(__float_as_uint(v), 0x401F));
}
#define MFMA(a, b, c) __builtin_amdgcn_mfma_f32_16x16x16f16((a), (b), (c), 0, 0, 0)
#define LND(x) asm volatile("" : "+v"(x))

DEV v4h cvt_hi(v4f x) {
    v4h r;
#pragma unroll
    for (int i = 0; i < 4; ++i) r[i] = (_Float16)x[i];
    return r;
}
DEV v4h cvt_lo(v4f x, v4h hi) {
    v4h r;
#pragma unroll
    for (int i = 0; i < 4; ++i) r[i] = (_Float16)(x[i] - (float)hi[i]);
    return r;
}

// ---------------- ws layout (float offsets) ----------------
constexpr size_t ACC   = 0;                 // 64  (2 tracks x (16 sum + 16 sumsq))
constexpr size_t LO    = 128;               // 65536  Lo[64][128][8]
constexpr size_t RO    = LO + 65536;        // 65536  Ro[64][128][8]
constexpr size_t HBUF  = RO + 65536;        // 262144 h[track][8192][16]
constexpr size_t XW0   = HBUF + 262144;     // 393216 xw0[seq][t][48]
constexpr size_t ZLAST = XW0 + 393216;      // 1024   zlast[64][16]

// ===== K1: gate GRU via MFMA. 8 blocks x 64 thr; 16 seqs/wave. =====
// M packs layers (m0-7 = layer0 units, m8-15 = layer1). K packs [h0|h1].
// x fed via separate K-space matmul (k0-2). D/B layouts identical -> h feeds
// back with no cross-lane traffic. Online softmax (h1 bounded, no max).
__global__ __launch_bounds__(64, 1) void k1_gate(
    const float* __restrict__ Local, const float* __restrict__ Remote,
    const float* __restrict__ Wih0, const float* __restrict__ Whh0,
    const float* __restrict__ bih0, const float* __restrict__ bhh0,
    const float* __restrict__ Wih1, const float* __restrict__ Whh1,
    const float* __restrict__ bih1, const float* __restrict__ bhh1,
    float* __restrict__ ws)
{
    const int tid = threadIdx.x;
    const int blk = blockIdx.x;
    const int track = blk >> 2;
    const int b0 = (blk & 3) * 16;
    const int n_ = tid & 15;            // seq within group (B/D col)
    const int m  = tid & 15;            // A row
    const int kq = (tid >> 4) * 4;      // A k-range / D row-range base
    if (blk == 0) ws[ACC + tid] = 0.f;

    __shared__ __align__(16) float4 xs4[128 * 16];   // x(t) per seq, 32 KB

    const float* __restrict__ src = track ? Remote : Local;
    for (int i = tid; i < 2048; i += 64) {
        int t = i >> 4, n = i & 15;
        const float* p = src + ((size_t)(b0 + n) * 128 + t) * 132 + 128;
        xs4[t * 16 + n] = make_float4(p[0], p[1], p[2], 0.f);
    }

    // ---- A fragments (m = tid&15, k = kq+i) ----
    v4f f_rh, f_zh, f_ci, f_ch, f_rx, f_zx, f_cx;
#pragma unroll
    for (int i = 0; i < 4; ++i) {
        int k = kq + i;
        float rh, zh, ci, ch;
        if (m < 8) {
            rh = (k < 8) ? Whh0[m * 8 + k] : 0.f;
            zh = (k < 8) ? Whh0[(8 + m) * 8 + k] : 0.f;
            ci = 0.f;
            ch = (k < 8) ? Whh0[(16 + m) * 8 + k] : 0.f;
        } else {
            int j = m - 8;
            rh = (k < 8) ? Wih1[j * 8 + k] : Whh1[j * 8 + (k - 8)];
            zh = (k < 8) ? Wih1[(8 + j) * 8 + k] : Whh1[(8 + j) * 8 + (k - 8)];
            ci = (k < 8) ? Wih1[(16 + j) * 8 + k] : 0.f;
            ch = (k >= 8) ? Whh1[(16 + j) * 8 + (k - 8)] : 0.f;
        }
        f_rh[i] = rh; f_zh[i] = zh; f_ci[i] = ci; f_ch[i] = ch;
        bool xon = (m < 8) && (k < 3);
        f_rx[i] = xon ? Wih0[m * 3 + k] : 0.f;
        f_zx[i] = xon ? Wih0[(8 + m) * 3 + k] : 0.f;
        f_cx[i] = xon ? Wih0[(16 + m) * 3 + k] : 0.f;
    }
    v4h a_rh_hi = cvt_hi(f_rh), a_rh_lo = cvt_lo(f_rh, a_rh_hi);
    v4h a_zh_hi = cvt_hi(f_zh), a_zh_lo = cvt_lo(f_zh, a_zh_hi);
    v4h a_ci_hi = cvt_hi(f_ci), a_ci_lo = cvt_lo(f_ci, a_ci_hi);
    v4h a_ch_hi = cvt_hi(f_ch), a_ch_lo = cvt_lo(f_ch, a_ch_hi);
    v4h a_rx_hi = cvt_hi(f_rx), a_rx_lo = cvt_lo(f_rx, a_rx_hi);
    v4h a_zx_hi = cvt_hi(f_zx), a_zx_lo = cvt_lo(f_zx, a_zx_hi);
    v4h a_cx_hi = cvt_hi(f_cx), a_cx_lo = cvt_lo(f_cx, a_cx_hi);
    LND(a_rh_hi); LND(a_rh_lo); LND(a_zh_hi); LND(a_zh_lo);
    LND(a_ci_hi); LND(a_ci_lo); LND(a_ch_hi); LND(a_ch_lo);
    LND(a_rx_hi); LND(a_rx_lo); LND(a_zx_hi); LND(a_zx_lo);
    LND(a_cx_hi); LND(a_cx_lo);

    // ---- C-inits (D row mc = kq+i) ----
    v4f c_r, c_z, c_ci, c_ch;
#pragma unroll
    for (int i = 0; i < 4; ++i) {
        int mc = kq + i;
        if (mc < 8) {
            c_r[i]  = bih0[mc] + bhh0[mc];
            c_z[i]  = bih0[8 + mc] + bhh0[8 + mc];
            c_ci[i] = bih0[16 + mc];
            c_ch[i] = bhh0[16 + mc];
        } else {
            int j = mc - 8;
            c_r[i]  = bih1[j] + bhh1[j];
            c_z[i]  = bih1[8 + j] + bhh1[8 + j];
            c_ci[i] = bih1[16 + j];
            c_ch[i] = bhh1[16 + j];
        }
    }
    LND(c_r); LND(c_z); LND(c_ci); LND(c_ch);
    __syncthreads();

    float* __restrict__ outp = ws + (track ? RO : LO);
    const bool hi_half = (tid >= 32);

    v4f h = {0.f, 0.f, 0.f, 0.f};
    float4 xc = xs4[n_];
#pragma unroll 1
    for (int t = 0; t <= 128; ++t) {
        float4 xn = xs4[(t < 127 ? t + 1 : 127) * 16 + n_];
        v4h bh_hi = cvt_hi(h), bh_lo = cvt_lo(h, bh_hi);
        v4f xv = {xc.x, xc.y, xc.z, 0.f};
        v4h bx_hi = cvt_hi(xv), bx_lo = cvt_lo(xv, bx_hi);

        v4f Dr = c_r, Dz = c_z, Dci = c_ci, Dch = c_ch;
        Dr = MFMA(a_rh_hi, bh_hi, Dr); Dr = MFMA(a_rh_hi, bh_lo, Dr); Dr = MFMA(a_rh_lo, bh_hi, Dr);
        Dr = MFMA(a_rx_hi, bx_hi, Dr); Dr = MFMA(a_rx_hi, bx_lo, Dr); Dr = MFMA(a_rx_lo, bx_hi, Dr);
        Dz = MFMA(a_zh_hi, bh_hi, Dz); Dz = MFMA(a_zh_hi, bh_lo, Dz); Dz = MFMA(a_zh_lo, bh_hi, Dz);
        Dz = MFMA(a_zx_hi, bx_hi, Dz); Dz = MFMA(a_zx_hi, bx_lo, Dz); Dz = MFMA(a_zx_lo, bx_hi, Dz);
        Dci = MFMA(a_ci_hi, bh_hi, Dci); Dci = MFMA(a_ci_hi, bh_lo, Dci); Dci = MFMA(a_ci_lo, bh_hi, Dci);
        Dci = MFMA(a_cx_hi, bx_hi, Dci); Dci = MFMA(a_cx_hi, bx_lo, Dci); Dci = MFMA(a_cx_lo, bx_hi, Dci);
        Dch = MFMA(a_ch_hi, bh_hi, Dch); Dch = MFMA(a_ch_hi, bh_lo, Dch); Dch = MFMA(a_ch_lo, bh_hi, Dch);

        bool act = hi_half ? (t >= 1) : (t < 128);
#pragma unroll
        for (int i = 0; i < 4; ++i) {
            float r = fsig(Dr[i]);
            float z = fsig(Dz[i]);
            float n = ftanh_(Dci[i] + r * Dch[i]);
            float hv = n + z * (h[i] - n);
            h[i] = act ? hv : h[i];
        }

        // online softmax over h1 (lanes 32-63 hold layer-1 cells); |h1|<1 so no max
        if (t >= 1) {
            float e0 = __expf(h[0]), e1 = __expf(h[1]), e2 = __expf(h[2]), e3 = __expf(h[3]);
            float ps = e0 + e1 + e2 + e3;
            float po = swz16f(ps);
            float inv = __builtin_amdgcn_rcpf(ps + po);
            if (hi_half) {
                float4 o = make_float4(e0 * inv, e1 * inv, e2 * inv, e3 * inv);
                *(float4*)(outp + ((size_t)(b0 + n_) * 128 + (t - 1)) * 8 + (kq - 8)) = o;
            }
        }
        xc = xn;
    }
}

// ====== K2: expert layer-1 GEMM + gate mix + batch-stat accumulation ======
__global__ __launch_bounds__(256) void k2_expert1(
    const float* __restrict__ Local, const float* __restrict__ Remote,
    const float* __restrict__ ae_w1, const float* __restrict__ ae_b1,
    float* __restrict__ ws)
{
    const int blk = blockIdx.x;
    const int track = blk >> 7;
    const int n0 = (blk & 127) * 64;
    const float* __restrict__ X = track ? Remote : Local;
    const float* __restrict__ om = ws + (track ? RO : LO);

    __shared__ __align__(16) float xsh[64 * 132];
    __shared__ __align__(16) float wsh[16 * 1040];
    __shared__ float omsh[64][8];
    __shared__ float b1sh[128];
    __shared__ float red[32];
    const int tid = threadIdx.x;

    for (int i = tid; i < 2048; i += 256) {
        int r = i >> 5, q = i & 31;
        ((float4*)&xsh[r * 132])[q] = ((const float4*)(X + (size_t)(n0 + r) * 132))[q];
    }
    for (int i4 = tid; i4 < 4096; i4 += 256) {
        float4 v = ((const float4*)ae_w1)[i4];
        int i = i4 * 4;
#pragma unroll
        for (int c = 0; c < 4; ++c) {
            int ii = i + c;
            int h = ii & 15, kk = (ii >> 4) & 127, e = ii >> 11;
            float vc = c == 0 ? v.x : c == 1 ? v.y : c == 2 ? v.z : v.w;
            wsh[h * 1040 + e * 130 + kk] = vc;
        }
    }
    for (int i = tid; i < 512; i += 256) omsh[i >> 3][i & 7] = om[(size_t)(n0 + (i >> 3)) * 8 + (i & 7)];
    for (int i = tid; i < 128; i += 256) b1sh[i] = ae_b1[i];
    if (tid < 32) red[tid] = 0.f;
    __syncthreads();

    const int hh = tid & 15, rg = tid >> 4;
    float acc[4][8];
#pragma unroll
    for (int r = 0; r < 4; ++r)
#pragma unroll
        for (int e = 0; e < 8; ++e) acc[r][e] = 0.f;

#pragma unroll 4
    for (int kq = 0; kq < 32; ++kq) {
        float4 xv[4], wv[8];
#pragma unroll
        for (int r = 0; r < 4; ++r) xv[r] = *(const float4*)&xsh[(rg * 4 + r) * 132 + kq * 4];
#pragma unroll
        for (int e = 0; e < 8; ++e) wv[e] = *(const float4*)&wsh[hh * 1040 + e * 130 + kq * 4];
#pragma unroll
        for (int r = 0; r < 4; ++r)
#pragma unroll
            for (int e = 0; e < 8; ++e) {
                float a = acc[r][e];
                a = fmaf(xv[r].x, wv[e].x, a);
                a = fmaf(xv[r].y, wv[e].y, a);
                a = fmaf(xv[r].z, wv[e].z, a);
                a = fmaf(xv[r].w, wv[e].w, a);
                acc[r][e] = a;
            }
    }

    float s = 0.f, s2 = 0.f;
    float* __restrict__ hout = ws + HBUF + (size_t)track * 131072;
#pragma unroll
    for (int r = 0; r < 4; ++r) {
        int row = rg * 4 + r;
        float hv = 0.f;
#pragma unroll
        for (int e = 0; e < 8; ++e) hv = fmaf(omsh[row][e], acc[r][e] + b1sh[e * 16 + hh], hv);
        hout[(size_t)(n0 + row) * 16 + hh] = hv;
        s += hv; s2 += hv * hv;
    }
    __syncthreads();
    atomicAdd(&red[hh], s);
    atomicAdd(&red[16 + hh], s2);
    __syncthreads();
    if (tid < 32) atomicAdd(&ws[ACC + track * 32 + tid], red[tid]);
}

// ====== K3: BN finalize + ELU + expert layer-2 + Z=ZL+ZR + xw0 precompute ======
__global__ __launch_bounds__(256) void k3_bn_mlp2(
    const float* __restrict__ ae_w2, const float* __restrict__ ae_b2,
    const float* __restrict__ ae_g, const float* __restrict__ ae_bt,
    const float* __restrict__ mWih0, const float* __restrict__ mbih0,
    float* __restrict__ ws)
{
    const int n0 = blockIdx.x * 64;
    const int tid = threadIdx.x;
    __shared__ float actsh[2][64][16];
    __shared__ float omsh[2][64][8];
    __shared__ float w2sh[2048];
    __shared__ float b2sh[128];
    __shared__ float zsh[64][17];
    __shared__ float wihsh[48][17];
    __shared__ float bihsh[48];
    __shared__ float stat[4][16];

    if (tid < 32) {
        int trk = tid >> 4, h = tid & 15;
        float s = ws[ACC + trk * 32 + h], s2 = ws[ACC + trk * 32 + 16 + h];
        float m = s * (1.f / 8192.f);
        float v = fmaxf(s2 * (1.f / 8192.f) - m * m, 0.f);
        stat[trk * 2][h] = m;
        stat[trk * 2 + 1][h] = rsqrtf(v + 1e-5f);
    }
    for (int i = tid; i < 2048; i += 256) w2sh[i] = ae_w2[i];
    for (int i = tid; i < 128; i += 256) b2sh[i] = ae_b2[i];
    for (int i = tid; i < 768; i += 256) wihsh[i >> 4][i & 15] = mWih0[i];
    if (tid < 48) bihsh[tid] = mbih0[tid];
    for (int i = tid; i < 1024; i += 256) {
        int trk = i >> 9, r = (i >> 3) & 63, e = i & 7;
        omsh[trk][r][e] = ws[(trk ? RO : LO) + (size_t)(n0 + r) * 8 + e];
    }
    __syncthreads();

    for (int i = tid; i < 2048; i += 256) {
        int trk = i >> 10, r = (i >> 4) & 63, h = i & 15;
        float v = ws[HBUF + (size_t)trk * 131072 + (size_t)(n0 + r) * 16 + h];
        float a = ae_g[h] * (v - stat[trk * 2][h]) * stat[trk * 2 + 1][h] + ae_bt[h];
        actsh[trk][r][h] = a > 0.f ? a : expm1f(a);
    }
    __syncthreads();

    for (int i = tid; i < 1024; i += 256) {
        int r = i >> 4, o = i & 15;
        float accv = 0.f;
#pragma unroll
        for (int trk = 0; trk < 2; ++trk) {
#pragma unroll
            for (int e = 0; e < 8; ++e) {
                const float* w = &w2sh[e * 256 + o];
                float t = b2sh[e * 16 + o];
#pragma unroll
                for (int h = 0; h < 16; ++h) t = fmaf(actsh[trk][r][h], w[h * 16], t);
                accv = fmaf(omsh[trk][r][e], t, accv);
            }
        }
        zsh[r][o] = accv;
    }
    __syncthreads();

    // xw0[(seq*128+t)*48 + g*16 + m] = bih0 + mWih0 . Z   (gr = g*16+m)
    for (int i = tid; i < 3072; i += 256) {
        int r = i / 48, gr = i - r * 48;
        float a = bihsh[gr];
#pragma unroll
        for (int k = 0; k < 16; ++k) a = fmaf(zsh[r][k], wihsh[gr][k], a);
        ws[XW0 + (size_t)(n0 + r) * 48 + gr] = a;
    }
}

// ===== K4: main GRU via MFMA. 4 blocks x 64 thr; 16 seqs/wave. =====
// Layer0 and layer1 each a 16-row matmul set; xw0 (i-side of layer0, incl
// bih0) streamed from global with 1-step prefetch. 27 MFMAs/step.
__global__ __launch_bounds__(64, 1) void k4_maingru(
    const float* __restrict__ Whh0, const float* __restrict__ bhh0,
    const float* __restrict__ Wih1, const float* __restrict__ Whh1,
    const float* __restrict__ bih1, const float* __restrict__ bhh1,
    float* __restrict__ ws)
{
    const int tid = threadIdx.x;
    const int seqbase = blockIdx.x * 16;
    const int n_ = tid & 15;
    const int m  = tid & 15;
    const int kq = (tid >> 4) * 4;

    // ---- A fragments ----
    v4f f;
#define FRAG(name, W, rowbase) \
    { float4 w4 = *(const float4*)&(W)[((rowbase) + m) * 16 + kq]; \
      f[0] = w4.x; f[1] = w4.y; f[2] = w4.z; f[3] = w4.w; } \
    v4h name##_hi = cvt_hi(f); v4h name##_lo = cvt_lo(f, name##_hi); \
    LND(name##_hi); LND(name##_lo);
    FRAG(a_rh0, Whh0, 0)
    FRAG(a_zh0, Whh0, 16)
    FRAG(a_ch0, Whh0, 32)
    FRAG(a_ri1, Wih1, 0)
    FRAG(a_rh1, Whh1, 0)
    FRAG(a_zi1, Wih1, 16)
    FRAG(a_zh1, Whh1, 16)
    FRAG(a_ci1, Wih1, 32)
    FRAG(a_ch1, Whh1, 32)
#undef FRAG

    // ---- C-inits (D row mc = kq+i) ----
    v4f c_r0, c_z0, c_ch0, c_r1, c_z1, c_ci1, c_ch1;
#pragma unroll
    for (int i = 0; i < 4; ++i) {
        int mc = kq + i;
        c_r0[i]  = bhh0[mc];
        c_z0[i]  = bhh0[16 + mc];
        c_ch0[i] = bhh0[32 + mc];
        c_r1[i]  = bih1[mc] + bhh1[mc];
        c_z1[i]  = bih1[16 + mc] + bhh1[16 + mc];
        c_ci1[i] = bih1[32 + mc];
        c_ch1[i] = bhh1[32 + mc];
    }
    LND(c_r0); LND(c_z0); LND(c_ch0); LND(c_r1); LND(c_z1); LND(c_ci1); LND(c_ch1);

    // xw0 stream: ws[XW0 + (seq*128+t)*48 + g*16 + kq..]
    const float* __restrict__ xwb = ws + XW0 + (size_t)(seqbase + n_) * 128 * 48 + kq;
    float4 xr = *(const float4*)(xwb + 0);
    float4 xz = *(const float4*)(xwb + 16);
    float4 xn2 = *(const float4*)(xwb + 32);

    v4f h0 = {0.f, 0.f, 0.f, 0.f};
    v4f h1 = {0.f, 0.f, 0.f, 0.f};
#pragma unroll 1
    for (int t = 0; t <= 128; ++t) {
        int tn = (t < 127 ? t + 1 : 127) * 48;
        float4 qr = *(const float4*)(xwb + tn);
        float4 qz = *(const float4*)(xwb + tn + 16);
        float4 qc = *(const float4*)(xwb + tn + 32);

        v4h b0_hi = cvt_hi(h0), b0_lo = cvt_lo(h0, b0_hi);
        v4h b1_hi = cvt_hi(h1), b1_lo = cvt_lo(h1, b1_hi);

        v4f Dr0 = c_r0, Dz0 = c_z0, Dch0 = c_ch0;
        v4f Dr1 = c_r1, Dz1 = c_z1, Dci1 = c_ci1, Dch1 = c_ch1;
        Dr0 = MFMA(a_rh0_hi, b0_hi, Dr0); Dr0 = MFMA(a_rh0_hi, b0_lo, Dr0); Dr0 = MFMA(a_rh0_lo, b0_hi, Dr0);
        Dz0 = MFMA(a_zh0_hi, b0_hi, Dz0); Dz0 = MFMA(a_zh0_hi, b0_lo, Dz0); Dz0 = MFMA(a_zh0_lo, b0_hi, Dz0);
        Dch0 = MFMA(a_ch0_hi, b0_hi, Dch0); Dch0 = MFMA(a_ch0_hi, b0_lo, Dch0); Dch0 = MFMA(a_ch0_lo, b0_hi, Dch0);
        Dr1 = MFMA(a_ri1_hi, b0_hi, Dr1); Dr1 = MFMA(a_ri1_hi, b0_lo, Dr1); Dr1 = MFMA(a_ri1_lo, b0_hi, Dr1);
        Dr1 = MFMA(a_rh1_hi, b1_hi, Dr1); Dr1 = MFMA(a_rh1_hi, b1_lo, Dr1); Dr1 = MFMA(a_rh1_lo, b1_hi, Dr1);
        Dz1 = MFMA(a_zi1_hi, b0_hi, Dz1); Dz1 = MFMA(a_zi1_hi, b0_lo, Dz1); Dz1 = MFMA(a_zi1_lo, b0_hi, Dz1);
        Dz1 = MFMA(a_zh1_hi, b1_hi, Dz1); Dz1 = MFMA(a_zh1_hi, b1_lo, Dz1); Dz1 = MFMA(a_zh1_lo, b1_hi, Dz1);
        Dci1 = MFMA(a_ci1_hi, b0_hi, Dci1); Dci1 = MFMA(a_ci1_hi, b0_lo, Dci1); Dci1 = MFMA(a_ci1_lo, b0_hi, Dci1);
        Dch1 = MFMA(a_ch1_hi, b1_hi, Dch1); Dch1 = MFMA(a_ch1_hi, b1_lo, Dch1); Dch1 = MFMA(a_ch1_lo, b1_hi, Dch1);

        bool act0 = (t < 128), act1 = (t >= 1);
        float xrv[4] = {xr.x, xr.y, xr.z, xr.w};
        float xzv[4] = {xz.x, xz.y, xz.z, xz.w};
        float xcv[4] = {xn2.x, xn2.y, xn2.z, xn2.w};
#pragma unroll
        for (int i = 0; i < 4; ++i) {
            float r0 = fsig(Dr0[i] + xrv[i]);
            float z0 = fsig(Dz0[i] + xzv[i]);
            float n0 = ftanh_(xcv[i] + r0 * Dch0[i]);
            float h0v = n0 + z0 * (h0[i] - n0);
            h0[i] = act0 ? h0v : h0[i];
            float r1 = fsig(Dr1[i]);
            float z1 = fsig(Dz1[i]);
            float n1 = ftanh_(Dci1[i] + r1 * Dch1[i]);
            float h1v = n1 + z1 * (h1[i] - n1);
            h1[i] = act1 ? h1v : h1[i];
        }
        xr = qr; xz = qz; xn2 = qc;
    }
    float4 o = make_float4(h1[0], h1[1], h1[2], h1[3]);
    *(float4*)(ws + ZLAST + (size_t)(seqbase + n_) * 16 + kq) = o;
}

// ===== K5: decoder MLP fused (layer1+BN redundant per block, layer2 slice) =====
__global__ __launch_bounds__(256) void k5_dec(
    const float* __restrict__ Remote,
    const float* __restrict__ md_w1, const float* __restrict__ md_b1,
    const float* __restrict__ md_g, const float* __restrict__ md_bt,
    const float* __restrict__ md_w2, const float* __restrict__ md_b2,
    const float* __restrict__ ws, float* __restrict__ out)
{
    const int o0 = blockIdx.x * 8;
    const int tid = threadIdx.x;
    __shared__ float xsh[64][17];
    __shared__ float omsh[64][8];
    __shared__ float w1sh[2176];
    __shared__ float b1sh[128];
    __shared__ float hsh[64][17];
    __shared__ float ssum[16], ss2[16], mstat[2][16];
    __shared__ float ash[64][17];
    __shared__ float w2sh[8][16][8];
    __shared__ float b2sh[8][8];

    for (int i = tid; i < 1024; i += 256) xsh[i >> 4][i & 15] = ws[ZLAST + i];
    if (tid < 64) xsh[tid][16] = Remote[((size_t)tid * 128 + 127) * 132 + 131];
    for (int i = tid; i < 512; i += 256)
        omsh[i >> 3][i & 7] = ws[RO + ((size_t)(i >> 3) * 128 + 127) * 8 + (i & 7)];
    for (int i = tid; i < 2176; i += 256) w1sh[i] = md_w1[i];
    for (int i = tid; i < 128; i += 256) b1sh[i] = md_b1[i];
    for (int i = tid; i < 1024; i += 256) {
        int e = i >> 7, h = (i >> 3) & 15, oo = i & 7;
        w2sh[e][h][oo] = md_w2[((size_t)e * 16 + h) * 128 + o0 + oo];
    }
    if (tid < 64) b2sh[tid >> 3][tid & 7] = md_b2[(size_t)(tid >> 3) * 128 + o0 + (tid & 7)];
    if (tid < 16) { ssum[tid] = 0.f; ss2[tid] = 0.f; }
    __syncthreads();

    for (int i = tid; i < 1024; i += 256) {
        int b = i >> 4, h = i & 15;
        float accv = 0.f;
#pragma unroll
        for (int e = 0; e < 8; ++e) {
            float t = b1sh[e * 16 + h];
            const float* w = &w1sh[e * 272 + h];
#pragma unroll
            for (int i2 = 0; i2 < 17; ++i2) t = fmaf(xsh[b][i2], w[i2 * 16], t);
            accv = fmaf(omsh[b][e], t, accv);
        }
        hsh[b][h] = accv;
        atomicAdd(&ssum[h], accv);
        atomicAdd(&ss2[h], accv * accv);
    }
    __syncthreads();
    if (tid < 16) {
        float m = ssum[tid] * (1.f / 64.f);
        float v = fmaxf(ss2[tid] * (1.f / 64.f) - m * m, 0.f);
        mstat[0][tid] = m;
        mstat[1][tid] = rsqrtf(v + 1e-5f);
    }
    __syncthreads();
    for (int i = tid; i < 1024; i += 256) {
        int b = i >> 4, h = i & 15;
        float a = md_g[h] * (hsh[b][h] - mstat[0][h]) * mstat[1][h] + md_bt[h];
        ash[b][h] = a > 0.f ? a : expm1f(a);
    }
    __syncthreads();

    for (int i = tid; i < 512; i += 256) {
        int b = i >> 3, oo = i & 7;
        float accv = 0.f;
#pragma unroll
        for (int e = 0; e < 8; ++e) {
            float t = b2sh[e][oo];
#pragma unroll
            for (int h = 0; h < 16; ++h) t = fmaf(ash[b][h], w2sh[e][h][oo], t);
            accv = fmaf(omsh[b][e], t, accv);
        }
        out[(size_t)b * 128 + o0 + oo] = accv;
    }
}

extern "C" void kernel_launch(void* const* d_in, const int* in_sizes, int n_in,
                              void* d_out, int out_size, void* d_ws, size_t ws_size,
                              hipStream_t stream) {
    const float* Local  = (const float*)d_in[0];
    const float* Remote = (const float*)d_in[1];
    const float* gWih0  = (const float*)d_in[2];
    const float* gWhh0  = (const float*)d_in[3];
    const float* gbih0  = (const float*)d_in[4];
    const float* gbhh0  = (const float*)d_in[5];
    const float* gWih1  = (const float*)d_in[6];
    const float* gWhh1  = (const float*)d_in[7];
    const float* gbih1  = (const float*)d_in[8];
    const float* gbhh1  = (const float*)d_in[9];
    const float* mWih0  = (const float*)d_in[10];
    const float* mWhh0  = (const float*)d_in[11];
    const float* mbih0  = (const float*)d_in[12];
    const float* mbhh0  = (const float*)d_in[13];
    const float* mWih1  = (const float*)d_in[14];
    const float* mWhh1  = (const float*)d_in[15];
    const float* mbih1  = (const float*)d_in[16];
    const float* mbhh1  = (const float*)d_in[17];
    const float* ae_w1  = (const float*)d_in[18];
    const float* ae_b1  = (const float*)d_in[19];
    const float* ae_w2  = (const float*)d_in[20];
    const float* ae_b2  = (const float*)d_in[21];
    const float* ae_g   = (const float*)d_in[22];
    const float* ae_bt  = (const float*)d_in[23];
    const float* md_w1  = (const float*)d_in[24];
    const float* md_b1  = (const float*)d_in[25];
    const float* md_w2  = (const float*)d_in[26];
    const float* md_b2  = (const float*)d_in[27];
    const float* md_g   = (const float*)d_in[28];
    const float* md_bt  = (const float*)d_in[29];
    float* ws  = (float*)d_ws;
    float* out = (float*)d_out;

    k1_gate<<<8, 64, 0, stream>>>(Local, Remote, gWih0, gWhh0, gbih0, gbhh0,
                                  gWih1, gWhh1, gbih1, gbhh1, ws);
    k2_expert1<<<256, 256, 0, stream>>>(Local, Remote, ae_w1, ae_b1, ws);
    k3_bn_mlp2<<<128, 256, 0, stream>>>(ae_w2, ae_b2, ae_g, ae_bt, mWih0, mbih0, ws);
    k4_maingru<<<4, 64, 0, stream>>>(mWhh0, mbhh0, mWih1, mWhh1, mbih1, mbhh1, ws);
    k5_dec<<<16, 256, 0, stream>>>(Remote, md_w1, md_b1, md_g, md_bt,
                                   md_w2, md_b2, ws, out);
}